// Round 19
// baseline (289.421 us; speedup 1.0000x reference)
//
#include <hip/hip_runtime.h>
#include <math.h>

#define VV  5
#define BB  32
#define NPP 20
#define NJJ 17
#define NBB 16
#define NDD 128
#define HID 1024
#define KPITCH 128          // padded kappa pitch (elements)
#define PRP 36              // padded pr row (34 used, 144B = 16B aligned)
#define VRP 20              // padded vr row (17 used, 80B = 16B aligned)
#define NCH 34              // partial channels: 17 A + 16 s2 + 1 mask
#define RGH_P 20            // ws_rough row pitch
#define BASE_P 52           // ws_base row pitch (51 used)
#define A2_ELEMS (64 * 4 * 64 * 8)            // 131072 u16 per buffer (16-row otiles, K=32 steps)
#define EPI2_ELEMS (64 * 64 * 16)             // 65536 floats

typedef __attribute__((ext_vector_type(8))) short short8;
typedef __attribute__((ext_vector_type(4))) float floatx4;

static constexpr int BONE_A[NBB] = {0,0,1,2,5,5,7,6,8,5,6,11,11,13,12,14};
static constexpr int BONE_B[NBB] = {1,2,3,4,6,7,9,8,10,11,12,12,13,15,14,16};

__device__ __forceinline__ float warp_red_sum(float v) {
#pragma unroll
  for (int off = 32; off >= 1; off >>= 1) v += __shfl_xor(v, off, 64);
  return v;
}

// ============ K0: A2 (16-row otiles, K=32 ksteps, lane-major) + epi2 pack (R18-exact) ============
__global__ __launch_bounds__(256) void prep_kernel(
    const float* __restrict__ Wc1, const float* __restrict__ Wc2,
    const float* __restrict__ bc1,
    unsigned short* __restrict__ A_hi, unsigned short* __restrict__ A_lo,
    float* __restrict__ epi) {
  int gidx = blockIdx.x * 256 + threadIdx.x;
  if (gidx < A2_ELEMS) {
    int e = gidx & 7;
    int l = (gidx >> 3) & 63;
    int rest = gidx >> 9;          // ot*4 + ks
    int ks = rest & 3;
    int ot = rest >> 2;            // 0..63
    int o = ot * 16 + (l & 15);
    int kk = ks * 32 + (l >> 4) * 8 + e;
    float x = (kk < 99) ? Wc1[o * 99 + kk] : 0.0f;
    unsigned int u = __float_as_uint(x);
    unsigned short hi = (unsigned short)(u >> 16);
    float xh = __uint_as_float((u >> 16) << 16);
    unsigned short lo = (unsigned short)(__float_as_uint(x - xh) >> 16);
    A_hi[gidx] = hi;
    A_lo[gidx] = lo;
  } else {
    int idx2 = gidx - A2_ELEMS;
    if (idx2 < EPI2_ELEMS) {
      int c = idx2 & 15;
      int l = (idx2 >> 4) & 63;
      int ot = idx2 >> 10;         // 0..63
      int base = ot * 16 + (l >> 4) * 4;
      epi[idx2] = (c < 12) ? Wc2[(base + c / 3) * 3 + (c % 3)] : bc1[base + (c - 12)];
    }
  }
}

// ============ K1a: rough-depth MLP + ray bases -> ws (R17-exact) ============
__global__ __launch_bounds__(256) void pose_pre_kernel(
    const float* __restrict__ kpts, const float* __restrict__ cam_R,
    const float* __restrict__ cam_f, const float* __restrict__ cam_c,
    const float* __restrict__ image_wh,
    const float* __restrict__ Wr1, const float* __restrict__ br1,
    const float* __restrict__ Wr2, const float* __restrict__ br2,
    float* __restrict__ ws_rough, float* __restrict__ ws_base) {
  const int n = blockIdx.x;
  const int b = n / NPP;
  const int p = n % NPP;
  const int tid = threadIdx.x;
  const int wv = tid >> 6, ln = tid & 63;

  __shared__ float sh_x[NJJ * 2];
  __shared__ float sh_h[HID];

  if (tid < NJJ * 2) {
    int j = tid >> 1, c = tid & 1;
    float k = kpts[((size_t)(b * NPP + p)) * NJJ * 2 + j * 2 + c];
    sh_x[tid] = k / image_wh[c];
  }
  __syncthreads();

#pragma unroll
  for (int k = 0; k < 4; ++k) {
    int m = tid + k * 256;
    float acc = br1[m];
#pragma unroll
    for (int c = 0; c < NJJ * 2; ++c) acc = fmaf(Wr1[m * (NJJ * 2) + c], sh_x[c], acc);
    sh_h[m] = fmaxf(acc, 0.0f);
  }
  __syncthreads();

  for (int j = wv; j < NJJ; j += 4) {
    float part = 0.0f;
    for (int m = ln; m < HID; m += 64) part = fmaf(Wr2[j * HID + m], sh_h[m], part);
    part = warp_red_sum(part);
    if (ln == 0) ws_rough[(size_t)n * RGH_P + j] = (part + br2[j]) * 1000.0f;
  }

  if (tid < NJJ) {
    int j = tid;
    const float* R0 = cam_R + (size_t)b * 9;
    float c0x = cam_c[b * 2 + 0], c0y = cam_c[b * 2 + 1];
    float f0x = cam_f[b * 2 + 0], f0y = cam_f[b * 2 + 1];
    float kx = kpts[((size_t)(b * NPP + p)) * NJJ * 2 + j * 2 + 0];
    float ky = kpts[((size_t)(b * NPP + p)) * NJJ * 2 + j * 2 + 1];
    float ux = (kx - c0x) / f0x;
    float uy = (ky - c0y) / f0y;
#pragma unroll
    for (int i = 0; i < 3; ++i)
      ws_base[(size_t)n * BASE_P + j * 3 + i] =
          R0[0 * 3 + i] * ux + R0[1 * 3 + i] * uy + R0[2 * 3 + i];
  }
}

// ============ K1b: matching -> per-view partials (R17 body; 6 blocks/CU) ============
__global__ __launch_bounds__(256, 6) void pose_match_kernel(
    const float* __restrict__ kpts, const float* __restrict__ joint_vis,
    const float* __restrict__ cam_R, const float* __restrict__ cam_T,
    const float* __restrict__ cam_f, const float* __restrict__ cam_c,
    const float* __restrict__ image_wh, const int* __restrict__ num_persons,
    const float* __restrict__ ws_rough, const float* __restrict__ ws_base,
    float* __restrict__ ws_partial) {
  const int bid = blockIdx.x;
  const int n = bid >> 1;
  const int bh = bid & 1;
  const int b = n / NPP;
  const int tid = threadIdx.x;
  const int rvv = tid >> 6;          // wave-uniform view index
  const int d = bh * 64 + (tid & 63);

  __shared__ float sh_rough[NJJ];
  __shared__ float sh_base[NJJ][3];
  __shared__ __align__(16) float sh_pr[4][NPP][PRP];
  __shared__ __align__(16) float sh_vr[4][NPP][VRP];

  if (tid < NJJ) sh_rough[tid] = ws_rough[(size_t)n * RGH_P + tid];
  if (tid >= 64 && tid < 64 + NJJ * 3)
    ((float*)sh_base)[tid - 64] = ws_base[(size_t)n * BASE_P + (tid - 64)];

#pragma unroll
  for (int rr = 0; rr < 4; ++rr) {
    const float* prg = kpts + ((size_t)(rr + 1) * BB + b) * NPP * NJJ * 2;
    for (int idx = tid; idx < NPP * NJJ * 2; idx += 256)
      sh_pr[rr][idx / 34][idx % 34] = prg[idx];
    const float* vrg = joint_vis + ((size_t)(rr + 1) * BB + b) * NPP * NJJ;
    for (int idx = tid; idx < NPP * NJJ; idx += 256)
      sh_vr[rr][idx / 17][idx % 17] = vrg[idx];
  }
  if (tid < 4 * BB) {
    int rr = tid >> 5, q = tid & 31;
    if (q < NPP) {
      sh_pr[rr][q][34] = 0.0f; sh_pr[rr][q][35] = 0.0f;
      sh_vr[rr][q][17] = 0.0f; sh_vr[rr][q][18] = 0.0f; sh_vr[rr][q][19] = 0.0f;
    }
  }
  __syncthreads();

  {
    const int rv = rvv + 1;
    const int vb = rv * BB + b;
    const float* Rr = cam_R + (size_t)vb * 9;
    const float R00 = Rr[0], R01 = Rr[1], R02 = Rr[2];
    const float R10 = Rr[3], R11 = Rr[4], R12 = Rr[5];
    const float R20 = Rr[6], R21 = Rr[7], R22 = Rr[8];
    const float Trx = cam_T[vb * 3 + 0], Try = cam_T[vb * 3 + 1], Trz = cam_T[vb * 3 + 2];
    const float frx = cam_f[vb * 2 + 0], fry = cam_f[vb * 2 + 1];
    const float crx = cam_c[vb * 2 + 0], cry = cam_c[vb * 2 + 1];
    const float wmax = image_wh[vb * 2 + 0] - 1.0f;
    const float hmax = image_wh[vb * 2 + 1] - 1.0f;
    const int nprv = num_persons[vb];
    const float T0x = cam_T[b * 3 + 0], T0y = cam_T[b * 3 + 1], T0z = cam_T[b * 3 + 2];
    const float lab = ((float)d / 127.0f) * 6000.0f + 2000.0f;

    float px[NJJ], py[NJJ];
#pragma unroll
    for (int j = 0; j < NJJ; ++j) {
      float dep = lab + sh_rough[j];
      float p0 = fmaf(dep, sh_base[j][0], T0x);
      float p1 = fmaf(dep, sh_base[j][1], T0y);
      float p2 = fmaf(dep, sh_base[j][2], T0z);
      float q0 = p0 - Trx, q1 = p1 - Try, q2 = p2 - Trz;
      float xc0 = R00 * q0 + R01 * q1 + R02 * q2;
      float xc1 = R10 * q0 + R11 * q1 + R12 * q2;
      float xc2 = R20 * q0 + R21 * q1 + R22 * q2 + 1e-8f;
      px[j] = xc0 / xc2 * frx + crx;
      py[j] = xc1 / xc2 * fry + cry;
    }

    float best = 3.4e38f;
    int mm = 0;
#pragma unroll 1
    for (int q = 0; q < NPP; ++q) {
      const float4* pr4 = (const float4*)(&sh_pr[rvv][q][0]);
      const float4* vr4 = (const float4*)(&sh_vr[rvv][q][0]);
      float num = 0.0f, den = 0.0f;
#pragma unroll
      for (int g4 = 0; g4 < 4; ++g4) {
        float4 w  = vr4[g4];
        float4 pa = pr4[2 * g4 + 0];
        float4 pb = pr4[2 * g4 + 1];
        { float dx = px[4*g4+0] - pa.x, dy = py[4*g4+0] - pa.y; num = fmaf(w.x, dx*dx + dy*dy, num); den += w.x; }
        { float dx = px[4*g4+1] - pa.z, dy = py[4*g4+1] - pa.w; num = fmaf(w.y, dx*dx + dy*dy, num); den += w.y; }
        { float dx = px[4*g4+2] - pb.x, dy = py[4*g4+2] - pb.y; num = fmaf(w.z, dx*dx + dy*dy, num); den += w.z; }
        { float dx = px[4*g4+3] - pb.z, dy = py[4*g4+3] - pb.w; num = fmaf(w.w, dx*dx + dy*dy, num); den += w.w; }
      }
      {
        float w16 = sh_vr[rvv][q][16];
        float4 pc = pr4[8];
        float dx = px[16] - pc.x, dy = py[16] - pc.y;
        num = fmaf(w16, dx*dx + dy*dy, num); den += w16;
      }
      float pd = num / (den + 1e-8f);
      if (q >= nprv) pd = 100000.0f;
      if (pd < best) { best = pd; mm = q; }
    }

    float* pbase = ws_partial + (((size_t)n * NCH) * 4 + rvv) * 128 + d;
    unsigned int maskB = 0u;
#pragma unroll
    for (int j = 0; j < NJJ; ++j) {
      float mx = sh_pr[rvv][mm][j * 2 + 0];
      float my = sh_pr[rvv][mm][j * 2 + 1];
      float mv = sh_vr[rvv][mm][j];
      float dx = px[j] - mx, dy = py[j] - my;
      float sc = expf(-sqrtf(dx * dx + dy * dy + 1e-12f) / 100.0f);
      float inb = (px[j] >= 0.0f && py[j] >= 0.0f && px[j] <= wmax && py[j] <= hmax) ? 1.0f : 0.0f;
      float bd = inb * mv;                 // exactly 0.0 or 1.0
      pbase[j * 512] = sc * bd;
      maskB |= ((unsigned int)(bd != 0.0f)) << j;
    }
    float v0 = sh_vr[rvv][mm][0];          // exactly 0.0 or 1.0
    maskB |= ((unsigned int)(v0 != 0.0f)) << 17;
#pragma unroll
    for (int nb = 0; nb < NBB; ++nb) {
      const int a = BONE_A[nb], c = BONE_B[nb];
      float ax = sh_pr[rvv][mm][a * 2 + 0], ay = sh_pr[rvv][mm][a * 2 + 1];
      float cx = sh_pr[rvv][mm][c * 2 + 0], cy = sh_pr[rvv][mm][c * 2 + 1];
      float dmx = ax - cx, dmy = ay - cy;
      float blm = sqrtf(dmx * dmx + dmy * dmy + 1e-12f);
      float dpx = px[a] - px[c], dpy = py[a] - py[c];
      float blp = sqrtf(dpx * dpx + dpy * dpy + 1e-12f);
      float scb = expf(-fabsf(blm - blp) / 5.0f);
      pbase[(NJJ + nb) * 512] = scb * v0;
    }
    *(unsigned int*)(pbase + 33 * 512) = maskB;
  }
}

// ============ K1.5: exact-order 4-view reduction -> xin (R17-exact) ============
__global__ __launch_bounds__(128) void reduce_kernel(
    const float* __restrict__ ws_partial, float* __restrict__ ws_xin) {
  const int n = blockIdx.x;
  const int t = threadIdx.x;
  const float* pb = ws_partial + ((size_t)n * NCH) * 4 * 128;
  float* xo = ws_xin + (size_t)n * (NJJ + NBB) * NDD;

  unsigned int m0 = __float_as_uint(pb[(33 * 4 + 0) * 128 + t]);
  unsigned int m1 = __float_as_uint(pb[(33 * 4 + 1) * 128 + t]);
  unsigned int m2 = __float_as_uint(pb[(33 * 4 + 2) * 128 + t]);
  unsigned int m3 = __float_as_uint(pb[(33 * 4 + 3) * 128 + t]);

#pragma unroll
  for (int i = 0; i < NJJ; ++i) {
    const float* a = pb + (i * 4) * 128 + t;
    float s = ((a[0] + a[128]) + a[256]) + a[384];
    int bj = ((m0 >> i) & 1) + ((m1 >> i) & 1) + ((m2 >> i) & 1) + ((m3 >> i) & 1);
    xo[i * NDD + t] = s / ((float)bj + 1e-8f);
  }
  int b2 = ((m0 >> 17) & 1) + ((m1 >> 17) & 1) + ((m2 >> 17) & 1) + ((m3 >> 17) & 1);
  float den2 = (float)b2 + 1e-8f;
#pragma unroll
  for (int nb = 0; nb < NBB; ++nb) {
    const float* a = pb + ((NJJ + nb) * 4) * 128 + t;
    float s = ((a[0] + a[128]) + a[256]) + a[384];
    xo[(NJJ + nb) * NDD + t] = s / den2;
  }
}

// ============ K2: 16x16x32 MFMA conv, half-bT ping-pong (3 blocks/CU) ============
__global__ __launch_bounds__(512, 6) void conv_mfma_kernel(
    const float* __restrict__ ws_xin,
    const unsigned short* __restrict__ A_hi, const unsigned short* __restrict__ A_lo,
    const float* __restrict__ epi,
    const float* __restrict__ bc2, float* __restrict__ out) {
  const int n = blockIdx.x;
  const int tid = threadIdx.x;
  const int w = tid >> 6;     // wave 0..7
  const int l = tid & 63;
  const int lcol = l & 15;    // t-col within 16-tile / A-row within tile
  const int lg = l >> 4;      // k-group 0..3

  __shared__ __align__(16) unsigned short bT_hi[64 * KPITCH];   // half t-range
  __shared__ __align__(16) unsigned short bT_lo[64 * KPITCH];
  __shared__ float plg[3][8][NDD];
  __shared__ float sh_l[NDD];
  __shared__ float sh_e[NDD];
  __shared__ float sh_sc[2];

  for (int i = tid; i < 3 * 8 * NDD; i += 512) ((float*)plg)[i] = 0.0f;

  const float* xn = ws_xin + (size_t)n * (NJJ + NBB) * NDD;
  const int sw = lcol << 3;

#pragma unroll 1
  for (int half = 0; half < 2; ++half) {
    __syncthreads();   // previous compute (or plg zero-init) done before restage

    // stage t-rows [half*64, half*64+64) -> local rows tl in [0,64)
    for (int idx = tid; idx < 64 * 64; idx += 512) {
      const int kp = (idx & 63) << 1;
      const int tl = idx >> 6;
      const int t = half * 64 + tl;
      unsigned int hp = 0, lp = 0;
#pragma unroll
      for (int u = 0; u < 2; ++u) {
        const int kk = kp + u;
        float x = 0.0f;
        if (kk < 99) {
          int i3 = kk / 3;
          int k3 = kk - i3 * 3;
          int tt = t + k3 - 1;
          if (tt >= 0 && tt < 128) x = xn[i3 * NDD + tt];
        }
        unsigned int uu = __float_as_uint(x);
        unsigned int hi = uu >> 16;
        float xh = __uint_as_float(hi << 16);
        unsigned int lo = __float_as_uint(x - xh) >> 16;
        hp |= hi << (16 * u);
        lp |= lo << (16 * u);
      }
      const int e = tl * KPITCH + (kp ^ ((tl & 15) << 3));
      *(unsigned int*)(bT_hi + e) = hp;
      *(unsigned int*)(bT_lo + e) = lp;
    }
    __syncthreads();

#pragma unroll 1
    for (int oi = 0; oi < 8; ++oi) {
      const int otg = w * 8 + oi;          // 16-row o-tile, 0..63

      short8 Ah[4], Al[4];
      {
        const short8* ahT = ((const short8*)A_hi) + (size_t)otg * 4 * 64 + l;
        const short8* alT = ((const short8*)A_lo) + (size_t)otg * 4 * 64 + l;
#pragma unroll
        for (int ks = 0; ks < 4; ++ks) {
          Ah[ks] = ahT[ks * 64];
          Al[ks] = alT[ks * 64];
        }
      }
      float w2f[12];
      float bcf[4];
      {
        const float4* ep = ((const float4*)epi) + ((size_t)otg * 64 + l) * 4;
        float4 e0 = ep[0], e1 = ep[1], e2 = ep[2], e3 = ep[3];
        w2f[0] = e0.x; w2f[1] = e0.y; w2f[2] = e0.z; w2f[3] = e0.w;
        w2f[4] = e1.x; w2f[5] = e1.y; w2f[6] = e1.z; w2f[7] = e1.w;
        w2f[8] = e2.x; w2f[9] = e2.y; w2f[10] = e2.z; w2f[11] = e2.w;
        bcf[0] = e3.x; bcf[1] = e3.y; bcf[2] = e3.z; bcf[3] = e3.w;
      }

#pragma unroll 1
      for (int tp = 0; tp < 2; ++tp) {
        const int t0l = tp * 32 + lcol;    // local row in [0,64)
        const int t1l = t0l + 16;
        const unsigned short* b0h = bT_hi + t0l * KPITCH;
        const unsigned short* b1h = bT_hi + t1l * KPITCH;
        const unsigned short* b0l = bT_lo + t0l * KPITCH;
        const unsigned short* b1l = bT_lo + t1l * KPITCH;

        floatx4 X0 = {0.f, 0.f, 0.f, 0.f}, Y0 = {0.f, 0.f, 0.f, 0.f};
        floatx4 X1 = {0.f, 0.f, 0.f, 0.f}, Y1 = {0.f, 0.f, 0.f, 0.f};

#pragma unroll
        for (int ks = 0; ks < 4; ++ks) {
          const int e = (ks * 32 + lg * 8) ^ sw;
          short8 bh0 = *(const short8*)(b0h + e);
          short8 bh1 = *(const short8*)(b1h + e);
          X0 = __builtin_amdgcn_mfma_f32_16x16x32_bf16(Ah[ks], bh0, X0, 0, 0, 0);
          Y0 = __builtin_amdgcn_mfma_f32_16x16x32_bf16(Al[ks], bh0, Y0, 0, 0, 0);
          X1 = __builtin_amdgcn_mfma_f32_16x16x32_bf16(Ah[ks], bh1, X1, 0, 0, 0);
          Y1 = __builtin_amdgcn_mfma_f32_16x16x32_bf16(Al[ks], bh1, Y1, 0, 0, 0);
        }
#pragma unroll
        for (int ks = 0; ks < 4; ++ks) {
          const int e = (ks * 32 + lg * 8) ^ sw;
          short8 bl0 = *(const short8*)(b0l + e);
          short8 bl1 = *(const short8*)(b1l + e);
          if (ks & 1) {
            Y0 = __builtin_amdgcn_mfma_f32_16x16x32_bf16(Ah[ks], bl0, Y0, 0, 0, 0);
            Y1 = __builtin_amdgcn_mfma_f32_16x16x32_bf16(Ah[ks], bl1, Y1, 0, 0, 0);
          } else {
            X0 = __builtin_amdgcn_mfma_f32_16x16x32_bf16(Ah[ks], bl0, X0, 0, 0, 0);
            X1 = __builtin_amdgcn_mfma_f32_16x16x32_bf16(Ah[ks], bl1, X1, 0, 0, 0);
          }
        }

        {
          float sP = 0.0f, sC = 0.0f, sM = 0.0f;
#pragma unroll
          for (int r = 0; r < 4; ++r) {
            float h = fmaxf((X0[r] + Y0[r]) + bcf[r], 0.0f);
            sP = fmaf(h, w2f[r * 3 + 0], sP);
            sC = fmaf(h, w2f[r * 3 + 1], sC);
            sM = fmaf(h, w2f[r * 3 + 2], sM);
          }
          sP += __shfl_xor(sP, 16, 64); sP += __shfl_xor(sP, 32, 64);
          sC += __shfl_xor(sC, 16, 64); sC += __shfl_xor(sC, 32, 64);
          sM += __shfl_xor(sM, 16, 64); sM += __shfl_xor(sM, 32, 64);
          if (lg == 0) {
            plg[0][w][half * 64 + t0l] += sP;
            plg[1][w][half * 64 + t0l] += sC;
            plg[2][w][half * 64 + t0l] += sM;
          }
        }
        {
          float sP = 0.0f, sC = 0.0f, sM = 0.0f;
#pragma unroll
          for (int r = 0; r < 4; ++r) {
            float h = fmaxf((X1[r] + Y1[r]) + bcf[r], 0.0f);
            sP = fmaf(h, w2f[r * 3 + 0], sP);
            sC = fmaf(h, w2f[r * 3 + 1], sC);
            sM = fmaf(h, w2f[r * 3 + 2], sM);
          }
          sP += __shfl_xor(sP, 16, 64); sP += __shfl_xor(sP, 32, 64);
          sC += __shfl_xor(sC, 16, 64); sC += __shfl_xor(sC, 32, 64);
          sM += __shfl_xor(sM, 16, 64); sM += __shfl_xor(sM, 32, 64);
          if (lg == 0) {
            plg[0][w][half * 64 + t1l] += sP;
            plg[1][w][half * 64 + t1l] += sC;
            plg[2][w][half * 64 + t1l] += sM;
          }
        }
      }
    }
  }
  __syncthreads();

  if (tid < NDD) {
    int t = tid;
    float lg2 = bc2[0];
#pragma unroll
    for (int ww = 0; ww < 8; ++ww) lg2 += plg[1][ww][t];
    if (t > 0) {
#pragma unroll
      for (int ww = 0; ww < 8; ++ww) lg2 += plg[0][ww][t - 1];
    }
    if (t < NDD - 1) {
#pragma unroll
      for (int ww = 0; ww < 8; ++ww) lg2 += plg[2][ww][t + 1];
    }
    sh_l[t] = lg2;
  }
  __syncthreads();
  if (tid < 64) {
    float v1 = sh_l[tid], v2 = sh_l[tid + 64];
    float mv; int mi;
    if (v2 > v1) { mv = v2; mi = tid + 64; } else { mv = v1; mi = tid; }
#pragma unroll
    for (int off = 32; off >= 1; off >>= 1) {
      float ov = __shfl_xor(mv, off, 64);
      int   oi2 = __shfl_xor(mi, off, 64);
      if (ov > mv || (ov == mv && oi2 < mi)) { mv = ov; mi = oi2; }
    }
    if (tid == 0) { sh_sc[0] = mv; ((int*)sh_sc)[1] = mi; }
  }
  __syncthreads();
  const float gmax = sh_sc[0];
  const int gidx = ((const int*)sh_sc)[1];
  if (tid < NDD) sh_e[tid] = expf(sh_l[tid] - gmax);
  __syncthreads();
  if (tid < 64) {
    float S = warp_red_sum(sh_e[tid] + sh_e[tid + 64]);
    float a1 = 0.0f, a2 = 0.0f;
#pragma unroll
    for (int k = 0; k < 2; ++k) {
      int t = tid + k * 64;
      float vol = sh_e[t] / S;
      float msk = (fabsf((float)t - (float)gidx) <= 5.0f) ? 1.0f : 0.0f;
      float mvv = vol * msk;
      a1 += mvv;
      a2 += mvv * (float)t;
    }
    a1 = warp_red_sum(a1);
    a2 = warp_red_sum(a2);
    if (tid == 0) {
      float pred = a2 / (a1 + 1e-8f);
      out[n] = pred / 127.0f * 6000.0f + 2000.0f;
    }
  }
}

extern "C" void kernel_launch(void* const* d_in, const int* in_sizes, int n_in,
                              void* d_out, int out_size, void* d_ws, size_t ws_size,
                              hipStream_t stream) {
  (void)in_sizes; (void)n_in; (void)out_size; (void)ws_size;
  const float* kpts        = (const float*)d_in[0];
  const float* joint_vis   = (const float*)d_in[2];
  const float* cam_R       = (const float*)d_in[5];
  const float* cam_T       = (const float*)d_in[6];
  const float* cam_f       = (const float*)d_in[7];
  const float* cam_c       = (const float*)d_in[8];
  const float* image_wh    = (const float*)d_in[9];
  const int*   num_persons = (const int*)d_in[10];
  const float* Wr1 = (const float*)d_in[11];
  const float* br1 = (const float*)d_in[12];
  const float* Wr2 = (const float*)d_in[13];
  const float* br2 = (const float*)d_in[14];
  const float* Wc1 = (const float*)d_in[15];
  const float* bc1 = (const float*)d_in[16];
  const float* Wc2 = (const float*)d_in[17];
  const float* bc2 = (const float*)d_in[18];
  float* out = (float*)d_out;

  unsigned short* A_hi = (unsigned short*)d_ws;               // 131072 u16
  unsigned short* A_lo = A_hi + A2_ELEMS;                     // 131072 u16
  float* epi        = (float*)(A_lo + A2_ELEMS);              // 65536 f32
  float* ws_xin     = epi + EPI2_ELEMS;                       // 640*33*128 f32
  float* ws_partial = ws_xin + (size_t)BB * NPP * (NJJ + NBB) * NDD;  // 640*34*4*128
  float* ws_rough   = ws_partial + (size_t)BB * NPP * NCH * 4 * 128;  // 640*20
  float* ws_base    = ws_rough + (size_t)BB * NPP * RGH_P;            // 640*52

  const int prep_items = A2_ELEMS + EPI2_ELEMS;
  hipLaunchKernelGGL(prep_kernel, dim3((prep_items + 255) / 256), dim3(256), 0, stream,
                     Wc1, Wc2, bc1, A_hi, A_lo, epi);
  hipLaunchKernelGGL(pose_pre_kernel, dim3(BB * NPP), dim3(256), 0, stream,
                     kpts, cam_R, cam_f, cam_c, image_wh, Wr1, br1, Wr2, br2,
                     ws_rough, ws_base);
  hipLaunchKernelGGL(pose_match_kernel, dim3(BB * NPP * 2), dim3(256), 0, stream,
                     kpts, joint_vis, cam_R, cam_T, cam_f, cam_c, image_wh,
                     num_persons, ws_rough, ws_base, ws_partial);
  hipLaunchKernelGGL(reduce_kernel, dim3(BB * NPP), dim3(128), 0, stream,
                     ws_partial, ws_xin);
  hipLaunchKernelGGL(conv_mfma_kernel, dim3(BB * NPP), dim3(512), 0, stream,
                     ws_xin, A_hi, A_lo, epi, bc2, out);
}

// Round 20
// 181.587 us; speedup vs baseline: 1.5938x; 1.5938x over previous
//
#include <hip/hip_runtime.h>
#include <math.h>

#define VV  5
#define BB  32
#define NPP 20
#define NJJ 17
#define NBB 16
#define NDD 128
#define HID 1024
#define KPITCH 128          // padded kappa pitch (elements)
#define KSTEPS 7            // 7 * 16 = 112 >= 99
#define PRP 36              // padded pr row (34 used, 144B = 16B aligned)
#define VRP 20              // padded vr row (17 used, 80B = 16B aligned)
#define NCH 34              // partial channels: 17 A + 16 s2 + 1 mask
#define A_T_ELEMS (32 * KSTEPS * 64 * 8)      // 114688 u16 per buffer
#define EPI_ELEMS (32 * 4 * 64 * 16)          // 131072 floats

typedef __attribute__((ext_vector_type(8))) short short8;
typedef __attribute__((ext_vector_type(16))) float float16;

static constexpr int BONE_A[NBB] = {0,0,1,2,5,5,7,6,8,5,6,11,11,13,12,14};
static constexpr int BONE_B[NBB] = {1,2,3,4,6,7,9,8,10,11,12,12,13,15,14,16};

__device__ __forceinline__ float warp_red_sum(float v) {
#pragma unroll
  for (int off = 32; off >= 1; off >>= 1) v += __shfl_xor(v, off, 64);
  return v;
}

// ============ K0: build fragment-coalesced A_T (split bf16 hi/lo) + epi pack ============
__global__ __launch_bounds__(256) void prep_kernel(
    const float* __restrict__ Wc1, const float* __restrict__ Wc2,
    const float* __restrict__ bc1,
    unsigned short* __restrict__ A_hi, unsigned short* __restrict__ A_lo,
    float* __restrict__ epi) {
  int gidx = blockIdx.x * 256 + threadIdx.x;
  if (gidx < A_T_ELEMS) {
    int e = gidx & 7;
    int l = (gidx >> 3) & 63;
    int rest = gidx >> 9;          // ot*7 + ks
    int ks = rest % 7;
    int ot = rest / 7;
    int o = ot * 32 + (l & 31);
    int kk = ks * 16 + (l >> 5) * 8 + e;
    float x = (kk < 99) ? Wc1[o * 99 + kk] : 0.0f;
    unsigned int u = __float_as_uint(x);
    unsigned short hi = (unsigned short)(u >> 16);
    float xh = __uint_as_float((u >> 16) << 16);
    unsigned short lo = (unsigned short)(__float_as_uint(x - xh) >> 16);
    A_hi[gidx] = hi;
    A_lo[gidx] = lo;
  } else {
    int idx2 = gidx - A_T_ELEMS;
    if (idx2 < EPI_ELEMS) {
      int c = idx2 & 15;
      int l = (idx2 >> 4) & 63;
      int rb = (idx2 >> 10) & 3;
      int ot = idx2 >> 12;
      int base = ot * 32 + 4 * (l >> 5) + 8 * rb;
      epi[idx2] = (c < 12) ? Wc2[base * 3 + c] : bc1[base + (c - 12)];
    }
  }
}

// ===================== K1: geometry + matching -> per-view partials =====================
// Streams 34 channels per (view,depth) thread straight to ws_partial.
// Layout: ws_partial[((n*NCH + ch)*4 + rvv)*128 + d].
__global__ __launch_bounds__(512, 4) void pose_front_kernel(
    const float* __restrict__ kpts, const float* __restrict__ joint_vis,
    const float* __restrict__ cam_R, const float* __restrict__ cam_T,
    const float* __restrict__ cam_f, const float* __restrict__ cam_c,
    const float* __restrict__ image_wh, const int* __restrict__ num_persons,
    const float* __restrict__ Wr1, const float* __restrict__ br1,
    const float* __restrict__ Wr2, const float* __restrict__ br2,
    float* __restrict__ ws_partial) {
  const int n = blockIdx.x;
  const int b = n / NPP;
  const int p = n % NPP;
  const int tid = threadIdx.x;
  const int wv = tid >> 6, ln = tid & 63;
  const int rvv = tid >> 7;          // 0..3 -> view rvv+1 (wave-uniform)
  const int d   = tid & (NDD - 1);   // depth bin

  __shared__ float sh_x[NJJ * 2];
  __shared__ float sh_h[HID];
  __shared__ float sh_rough[NJJ];
  __shared__ float sh_base[NJJ][3];
  __shared__ __align__(16) float sh_pr[4][NPP][PRP];
  __shared__ __align__(16) float sh_vr[4][NPP][VRP];

  if (tid < NJJ * 2) {
    int j = tid >> 1, c = tid & 1;
    float k = kpts[((size_t)(b * NPP + p)) * NJJ * 2 + j * 2 + c];
    sh_x[tid] = k / image_wh[c];
  }
  __syncthreads();

#pragma unroll
  for (int k = 0; k < 2; ++k) {
    int m = tid + k * 512;
    float acc = br1[m];
#pragma unroll
    for (int c = 0; c < NJJ * 2; ++c) acc = fmaf(Wr1[m * (NJJ * 2) + c], sh_x[c], acc);
    sh_h[m] = fmaxf(acc, 0.0f);
  }
  __syncthreads();

  for (int j = wv; j < NJJ; j += 8) {
    float part = 0.0f;
    for (int m = ln; m < HID; m += 64) part = fmaf(Wr2[j * HID + m], sh_h[m], part);
    part = warp_red_sum(part);
    if (ln == 0) sh_rough[j] = (part + br2[j]) * 1000.0f;
  }
  if (tid < NJJ) {
    int j = tid;
    const float* R0 = cam_R + (size_t)b * 9;
    float c0x = cam_c[b * 2 + 0], c0y = cam_c[b * 2 + 1];
    float f0x = cam_f[b * 2 + 0], f0y = cam_f[b * 2 + 1];
    float kx = kpts[((size_t)(b * NPP + p)) * NJJ * 2 + j * 2 + 0];
    float ky = kpts[((size_t)(b * NPP + p)) * NJJ * 2 + j * 2 + 1];
    float ux = (kx - c0x) / f0x;
    float uy = (ky - c0y) / f0y;
#pragma unroll
    for (int i = 0; i < 3; ++i)
      sh_base[j][i] = R0[0 * 3 + i] * ux + R0[1 * 3 + i] * uy + R0[2 * 3 + i];
  }
#pragma unroll
  for (int rr = 0; rr < 4; ++rr) {
    const float* prg = kpts + ((size_t)(rr + 1) * BB + b) * NPP * NJJ * 2;
    for (int idx = tid; idx < NPP * NJJ * 2; idx += 512)
      sh_pr[rr][idx / 34][idx % 34] = prg[idx];
    const float* vrg = joint_vis + ((size_t)(rr + 1) * BB + b) * NPP * NJJ;
    for (int idx = tid; idx < NPP * NJJ; idx += 512)
      sh_vr[rr][idx / 17][idx % 17] = vrg[idx];
  }
  if (tid < 4 * BB) {
    int rr = tid >> 5, q = tid & 31;
    if (q < NPP) {
      sh_pr[rr][q][34] = 0.0f; sh_pr[rr][q][35] = 0.0f;
      sh_vr[rr][q][17] = 0.0f; sh_vr[rr][q][18] = 0.0f; sh_vr[rr][q][19] = 0.0f;
    }
  }
  __syncthreads();

  {
    const int rv = rvv + 1;
    const int vb = rv * BB + b;
    const float* Rr = cam_R + (size_t)vb * 9;
    const float R00 = Rr[0], R01 = Rr[1], R02 = Rr[2];
    const float R10 = Rr[3], R11 = Rr[4], R12 = Rr[5];
    const float R20 = Rr[6], R21 = Rr[7], R22 = Rr[8];
    const float Trx = cam_T[vb * 3 + 0], Try = cam_T[vb * 3 + 1], Trz = cam_T[vb * 3 + 2];
    const float frx = cam_f[vb * 2 + 0], fry = cam_f[vb * 2 + 1];
    const float crx = cam_c[vb * 2 + 0], cry = cam_c[vb * 2 + 1];
    const float wmax = image_wh[vb * 2 + 0] - 1.0f;
    const float hmax = image_wh[vb * 2 + 1] - 1.0f;
    const int nprv = num_persons[vb];
    const float T0x = cam_T[b * 3 + 0], T0y = cam_T[b * 3 + 1], T0z = cam_T[b * 3 + 2];
    const float lab = ((float)d / 127.0f) * 6000.0f + 2000.0f;

    float px[NJJ], py[NJJ];
#pragma unroll
    for (int j = 0; j < NJJ; ++j) {
      float dep = lab + sh_rough[j];
      float p0 = fmaf(dep, sh_base[j][0], T0x);
      float p1 = fmaf(dep, sh_base[j][1], T0y);
      float p2 = fmaf(dep, sh_base[j][2], T0z);
      float q0 = p0 - Trx, q1 = p1 - Try, q2 = p2 - Trz;
      float xc0 = R00 * q0 + R01 * q1 + R02 * q2;
      float xc1 = R10 * q0 + R11 * q1 + R12 * q2;
      float xc2 = R20 * q0 + R21 * q1 + R22 * q2 + 1e-8f;
      px[j] = xc0 / xc2 * frx + crx;
      py[j] = xc1 / xc2 * fry + cry;
    }

    // argmin over candidates (exact first-min)
    float best = 3.4e38f;
    int mm = 0;
#pragma unroll 1
    for (int q = 0; q < NPP; ++q) {
      const float4* pr4 = (const float4*)(&sh_pr[rvv][q][0]);
      const float4* vr4 = (const float4*)(&sh_vr[rvv][q][0]);
      float num = 0.0f, den = 0.0f;
#pragma unroll
      for (int g4 = 0; g4 < 4; ++g4) {
        float4 w  = vr4[g4];
        float4 pa = pr4[2 * g4 + 0];
        float4 pb = pr4[2 * g4 + 1];
        { float dx = px[4*g4+0] - pa.x, dy = py[4*g4+0] - pa.y; num = fmaf(w.x, dx*dx + dy*dy, num); den += w.x; }
        { float dx = px[4*g4+1] - pa.z, dy = py[4*g4+1] - pa.w; num = fmaf(w.y, dx*dx + dy*dy, num); den += w.y; }
        { float dx = px[4*g4+2] - pb.x, dy = py[4*g4+2] - pb.y; num = fmaf(w.z, dx*dx + dy*dy, num); den += w.z; }
        { float dx = px[4*g4+3] - pb.z, dy = py[4*g4+3] - pb.w; num = fmaf(w.w, dx*dx + dy*dy, num); den += w.w; }
      }
      {
        float w16 = sh_vr[rvv][q][16];
        float4 pc = pr4[8];
        float dx = px[16] - pc.x, dy = py[16] - pc.y;
        num = fmaf(w16, dx*dx + dy*dy, num); den += w16;
      }
      float pd = num / (den + 1e-8f);
      if (q >= nprv) pd = 100000.0f;
      if (pd < best) { best = pd; mm = q; }
    }

    // stream channels straight to ws_partial (no arrays, no barriers)
    float* pbase = ws_partial + (((size_t)n * NCH) * 4 + rvv) * 128 + d;
    unsigned int maskB = 0u;
#pragma unroll
    for (int j = 0; j < NJJ; ++j) {
      float mx = sh_pr[rvv][mm][j * 2 + 0];
      float my = sh_pr[rvv][mm][j * 2 + 1];
      float mv = sh_vr[rvv][mm][j];
      float dx = px[j] - mx, dy = py[j] - my;
      float sc = expf(-sqrtf(dx * dx + dy * dy + 1e-12f) / 100.0f);
      float inb = (px[j] >= 0.0f && py[j] >= 0.0f && px[j] <= wmax && py[j] <= hmax) ? 1.0f : 0.0f;
      float bd = inb * mv;                 // exactly 0.0 or 1.0
      pbase[j * 512] = sc * bd;            // A channel j
      maskB |= ((unsigned int)(bd != 0.0f)) << j;
    }
    float v0 = sh_vr[rvv][mm][0];          // exactly 0.0 or 1.0
    maskB |= ((unsigned int)(v0 != 0.0f)) << 17;
#pragma unroll
    for (int nb = 0; nb < NBB; ++nb) {
      const int a = BONE_A[nb], c = BONE_B[nb];
      float ax = sh_pr[rvv][mm][a * 2 + 0], ay = sh_pr[rvv][mm][a * 2 + 1];
      float cx = sh_pr[rvv][mm][c * 2 + 0], cy = sh_pr[rvv][mm][c * 2 + 1];
      float dmx = ax - cx, dmy = ay - cy;
      float blm = sqrtf(dmx * dmx + dmy * dmy + 1e-12f);
      float dpx = px[a] - px[c], dpy = py[a] - py[c];
      float blp = sqrtf(dpx * dpx + dpy * dpy + 1e-12f);
      float scb = expf(-fabsf(blm - blp) / 5.0f);
      pbase[(NJJ + nb) * 512] = scb * v0;  // s2 channel
    }
    *(unsigned int*)(pbase + 33 * 512) = maskB;   // mask channel
  }
}

// ============ K1.5: exact-order 4-view reduction -> xin ============
__global__ __launch_bounds__(128) void reduce_kernel(
    const float* __restrict__ ws_partial, float* __restrict__ ws_xin) {
  const int n = blockIdx.x;
  const int t = threadIdx.x;
  const float* pb = ws_partial + ((size_t)n * NCH) * 4 * 128;
  float* xo = ws_xin + (size_t)n * (NJJ + NBB) * NDD;

  unsigned int m0 = __float_as_uint(pb[(33 * 4 + 0) * 128 + t]);
  unsigned int m1 = __float_as_uint(pb[(33 * 4 + 1) * 128 + t]);
  unsigned int m2 = __float_as_uint(pb[(33 * 4 + 2) * 128 + t]);
  unsigned int m3 = __float_as_uint(pb[(33 * 4 + 3) * 128 + t]);

#pragma unroll
  for (int i = 0; i < NJJ; ++i) {
    const float* a = pb + (i * 4) * 128 + t;
    float s = ((a[0] + a[128]) + a[256]) + a[384];   // rv1..rv4 exact order
    int bj = ((m0 >> i) & 1) + ((m1 >> i) & 1) + ((m2 >> i) & 1) + ((m3 >> i) & 1);
    xo[i * NDD + t] = s / ((float)bj + 1e-8f);
  }
  int b2 = ((m0 >> 17) & 1) + ((m1 >> 17) & 1) + ((m2 >> 17) & 1) + ((m3 >> 17) & 1);
  float den2 = (float)b2 + 1e-8f;
#pragma unroll
  for (int nb = 0; nb < NBB; ++nb) {
    const float* a = pb + ((NJJ + nb) * 4) * 128 + t;
    float s = ((a[0] + a[128]) + a[256]) + a[384];
    xo[(NJJ + nb) * NDD + t] = s / den2;
  }
}

// ============ K2: MFMA split-bf16 conv1 + fused conv2 + softmax readout ============
// Coalesced fragment-linear A_T / epi loads; X/Y chains; conflict-free
// paired staging; unroll-1 loops; LDS-accumulated plg (all proven pieces).
__global__ __launch_bounds__(512, 2) void conv_mfma_kernel(
    const float* __restrict__ ws_xin,
    const unsigned short* __restrict__ A_hi, const unsigned short* __restrict__ A_lo,
    const float* __restrict__ epi,
    const float* __restrict__ bc2, float* __restrict__ out) {
  const int n = blockIdx.x;
  const int tid = threadIdx.x;
  const int w = tid >> 6;     // wave 0..7
  const int l = tid & 63;
  const int lrow = l & 31;    // B-col (t) lane index
  const int g = l >> 5;       // k-half

  __shared__ __align__(16) unsigned short bT_hi[128 * KPITCH];
  __shared__ __align__(16) unsigned short bT_lo[128 * KPITCH];
  __shared__ float plg[3][8][NDD];
  __shared__ float sh_l[NDD];
  __shared__ float sh_e[NDD];
  __shared__ float sh_sc[2];

  for (int i = tid; i < 3 * 8 * NDD; i += 512) ((float*)plg)[i] = 0.0f;

  const float* xn = ws_xin + (size_t)n * (NJJ + NBB) * NDD;
  for (int idx = tid; idx < 64 * 128; idx += 512) {
    const int kp = (idx & 63) << 1;
    const int t  = idx >> 6;
    unsigned int hp = 0, lp = 0;
#pragma unroll
    for (int u = 0; u < 2; ++u) {
      const int kk = kp + u;
      float x = 0.0f;
      if (kk < 99) {
        int i3 = kk / 3;
        int k3 = kk - i3 * 3;
        int tt = t + k3 - 1;
        if (tt >= 0 && tt < 128) x = xn[i3 * NDD + tt];
      }
      unsigned int uu = __float_as_uint(x);
      unsigned int hi = uu >> 16;
      float xh = __uint_as_float(hi << 16);
      unsigned int lo = __float_as_uint(x - xh) >> 16;
      hp |= hi << (16 * u);
      lp |= lo << (16 * u);
    }
    const int e = t * KPITCH + (kp ^ ((t & 15) << 3));
    *(unsigned int*)(bT_hi + e) = hp;
    *(unsigned int*)(bT_lo + e) = lp;
  }
  __syncthreads();

#pragma unroll 1
  for (int otile = 0; otile < 4; ++otile) {
    const int otg = w * 4 + otile;       // global o-tile 0..31 (o0 = otg*32)

    short8 Ah[KSTEPS], Al[KSTEPS];
    {
      const short8* ahT = ((const short8*)A_hi) + (size_t)otg * KSTEPS * 64 + l;
      const short8* alT = ((const short8*)A_lo) + (size_t)otg * KSTEPS * 64 + l;
#pragma unroll
      for (int ks = 0; ks < KSTEPS; ++ks) {
        Ah[ks] = ahT[ks * 64];           // fully coalesced: lane-major layout
        Al[ks] = alT[ks * 64];
      }
    }
    // epilogue weights: coalesced lane-major epi pack
    float w2f[48];
    float bcf[16];
#pragma unroll
    for (int rb = 0; rb < 4; ++rb) {
      const float4* ep = ((const float4*)epi) + ((size_t)(otg * 4 + rb) * 64 + l) * 4;
      float4 e0 = ep[0], e1 = ep[1], e2 = ep[2], e3 = ep[3];
      w2f[rb * 12 + 0] = e0.x;  w2f[rb * 12 + 1] = e0.y;  w2f[rb * 12 + 2] = e0.z;
      w2f[rb * 12 + 3] = e0.w;  w2f[rb * 12 + 4] = e1.x;  w2f[rb * 12 + 5] = e1.y;
      w2f[rb * 12 + 6] = e1.z;  w2f[rb * 12 + 7] = e1.w;  w2f[rb * 12 + 8] = e2.x;
      w2f[rb * 12 + 9] = e2.y;  w2f[rb * 12 + 10] = e2.z; w2f[rb * 12 + 11] = e2.w;
      bcf[rb * 4 + 0] = e3.x; bcf[rb * 4 + 1] = e3.y;
      bcf[rb * 4 + 2] = e3.z; bcf[rb * 4 + 3] = e3.w;
    }

#pragma unroll 1
    for (int ttile = 0; ttile < 4; ++ttile) {
      const int trow = ttile * 32 + lrow;
      const unsigned short* brh = bT_hi + trow * KPITCH;
      const unsigned short* brl = bT_lo + trow * KPITCH;
      const int sw = (trow & 15) << 3;

      float16 X, Y;
#pragma unroll
      for (int r = 0; r < 16; ++r) { X[r] = 0.0f; Y[r] = 0.0f; }

#pragma unroll
      for (int ks = 0; ks < KSTEPS; ++ks) {
        const int e = (ks * 16 + g * 8) ^ sw;
        short8 bh = *(const short8*)(brh + e);
        X = __builtin_amdgcn_mfma_f32_32x32x16_bf16(Ah[ks], bh, X, 0, 0, 0);
        Y = __builtin_amdgcn_mfma_f32_32x32x16_bf16(Al[ks], bh, Y, 0, 0, 0);
      }
#pragma unroll
      for (int ks = 0; ks < KSTEPS; ++ks) {
        const int e = (ks * 16 + g * 8) ^ sw;
        short8 bl = *(const short8*)(brl + e);
        if (ks & 1) Y = __builtin_amdgcn_mfma_f32_32x32x16_bf16(Ah[ks], bl, Y, 0, 0, 0);
        else        X = __builtin_amdgcn_mfma_f32_32x32x16_bf16(Ah[ks], bl, X, 0, 0, 0);
      }

      float sP = 0.0f, sC = 0.0f, sM = 0.0f;
#pragma unroll
      for (int r = 0; r < 16; ++r) {
        float h = fmaxf((X[r] + Y[r]) + bcf[(r >> 2) * 4 + (r & 3)], 0.0f);
        sP = fmaf(h, w2f[(r >> 2) * 12 + (r & 3) * 3 + 0], sP);
        sC = fmaf(h, w2f[(r >> 2) * 12 + (r & 3) * 3 + 1], sC);
        sM = fmaf(h, w2f[(r >> 2) * 12 + (r & 3) * 3 + 2], sM);
      }
      sP += __shfl_xor(sP, 32, 64);
      sC += __shfl_xor(sC, 32, 64);
      sM += __shfl_xor(sM, 32, 64);
      if (l < 32) {
        plg[0][w][trow] += sP;
        plg[1][w][trow] += sC;
        plg[2][w][trow] += sM;
      }
    }
  }
  __syncthreads();

  if (tid < NDD) {
    int t = tid;
    float lg = bc2[0];
#pragma unroll
    for (int ww = 0; ww < 8; ++ww) lg += plg[1][ww][t];
    if (t > 0) {
#pragma unroll
      for (int ww = 0; ww < 8; ++ww) lg += plg[0][ww][t - 1];
    }
    if (t < NDD - 1) {
#pragma unroll
      for (int ww = 0; ww < 8; ++ww) lg += plg[2][ww][t + 1];
    }
    sh_l[t] = lg;
  }
  __syncthreads();
  if (tid < 64) {
    float v1 = sh_l[tid], v2 = sh_l[tid + 64];
    float mv; int mi;
    if (v2 > v1) { mv = v2; mi = tid + 64; } else { mv = v1; mi = tid; }
#pragma unroll
    for (int off = 32; off >= 1; off >>= 1) {
      float ov = __shfl_xor(mv, off, 64);
      int   oi = __shfl_xor(mi, off, 64);
      if (ov > mv || (ov == mv && oi < mi)) { mv = ov; mi = oi; }
    }
    if (tid == 0) { sh_sc[0] = mv; ((int*)sh_sc)[1] = mi; }
  }
  __syncthreads();
  const float gmax = sh_sc[0];
  const int gidx = ((const int*)sh_sc)[1];
  if (tid < NDD) sh_e[tid] = expf(sh_l[tid] - gmax);
  __syncthreads();
  if (tid < 64) {
    float S = warp_red_sum(sh_e[tid] + sh_e[tid + 64]);
    float a1 = 0.0f, a2 = 0.0f;
#pragma unroll
    for (int k = 0; k < 2; ++k) {
      int t = tid + k * 64;
      float vol = sh_e[t] / S;
      float msk = (fabsf((float)t - (float)gidx) <= 5.0f) ? 1.0f : 0.0f;
      float mvv = vol * msk;
      a1 += mvv;
      a2 += mvv * (float)t;
    }
    a1 = warp_red_sum(a1);
    a2 = warp_red_sum(a2);
    if (tid == 0) {
      float pred = a2 / (a1 + 1e-8f);
      out[n] = pred / 127.0f * 6000.0f + 2000.0f;
    }
  }
}

extern "C" void kernel_launch(void* const* d_in, const int* in_sizes, int n_in,
                              void* d_out, int out_size, void* d_ws, size_t ws_size,
                              hipStream_t stream) {
  (void)in_sizes; (void)n_in; (void)out_size; (void)ws_size;
  const float* kpts        = (const float*)d_in[0];
  const float* joint_vis   = (const float*)d_in[2];
  const float* cam_R       = (const float*)d_in[5];
  const float* cam_T       = (const float*)d_in[6];
  const float* cam_f       = (const float*)d_in[7];
  const float* cam_c       = (const float*)d_in[8];
  const float* image_wh    = (const float*)d_in[9];
  const int*   num_persons = (const int*)d_in[10];
  const float* Wr1 = (const float*)d_in[11];
  const float* br1 = (const float*)d_in[12];
  const float* Wr2 = (const float*)d_in[13];
  const float* br2 = (const float*)d_in[14];
  const float* Wc1 = (const float*)d_in[15];
  const float* bc1 = (const float*)d_in[16];
  const float* Wc2 = (const float*)d_in[17];
  const float* bc2 = (const float*)d_in[18];
  float* out = (float*)d_out;

  unsigned short* A_hi = (unsigned short*)d_ws;               // 114688 u16
  unsigned short* A_lo = A_hi + A_T_ELEMS;                    // 114688 u16
  float* epi        = (float*)(A_lo + A_T_ELEMS);             // 131072 f32
  float* ws_xin     = epi + EPI_ELEMS;                        // 640*33*128 f32
  float* ws_partial = ws_xin + (size_t)BB * NPP * (NJJ + NBB) * NDD;  // 640*34*4*128 f32

  const int prep_items = A_T_ELEMS + EPI_ELEMS;
  hipLaunchKernelGGL(prep_kernel, dim3((prep_items + 255) / 256), dim3(256), 0, stream,
                     Wc1, Wc2, bc1, A_hi, A_lo, epi);
  hipLaunchKernelGGL(pose_front_kernel, dim3(BB * NPP), dim3(512), 0, stream,
                     kpts, joint_vis, cam_R, cam_T, cam_f, cam_c, image_wh,
                     num_persons, Wr1, br1, Wr2, br2, ws_partial);
  hipLaunchKernelGGL(reduce_kernel, dim3(BB * NPP), dim3(128), 0, stream,
                     ws_partial, ws_xin);
  hipLaunchKernelGGL(conv_mfma_kernel, dim3(BB * NPP), dim3(512), 0, stream,
                     ws_xin, A_hi, A_lo, epi, bc2, out);
}